// Round 3
// baseline (12423.381 us; speedup 1.0000x reference)
//
#include <hip/hip_runtime.h>

#define RC 64
#define SC 64
#define NLAYERS 30
#define TT 64

// ---------------- start: h[b][c][t] = start_w[c]*x[b][t] + start_b[c] ----------------
__global__ __launch_bounds__(256) void wn_start(
    const float* __restrict__ x, const float* __restrict__ sw,
    const float* __restrict__ sb, float* __restrict__ h, int T)
{
    int t = blockIdx.x * blockDim.x + threadIdx.x;
    int b = blockIdx.y;
    float xv = x[(size_t)b * T + t];
    #pragma unroll
    for (int c = 0; c < RC; ++c)
        h[((size_t)b * RC + c) * T + t] = fmaf(sw[c], xv, sb[c]);
}

// ---------------- fused dilated-conv + gate + res + skip, one layer ----------------
// block = (64 t, 4 channel-groups); each thread owns 16 (filt,gate) channel pairs.
__global__ __launch_bounds__(256) void wn_layer(
    const float* __restrict__ h_in, float* __restrict__ h_out,
    float* __restrict__ skip_sum,
    const float* __restrict__ dw,   // [2RC][RC][2] layer slice
    const float* __restrict__ db,   // [2RC]
    const float* __restrict__ rw,   // [RC][RC]
    const float* __restrict__ rb,   // [RC]
    const float* __restrict__ skw,  // [SC][RC]
    const float* __restrict__ skb,  // [SC]
    int d, int T, int accum)
{
    __shared__ float sh_h[RC][TT + 1];  // h[k][t]
    __shared__ float sh_s[RC][TT + 1];  // h[k][t-d]
    __shared__ float sh_g[RC][TT + 1];  // gated[k][t]

    const int tx = threadIdx.x;   // 0..63 : t within tile
    const int y  = threadIdx.y;   // 0..3  : channel group (wave-uniform)
    const int b  = blockIdx.y;
    const int t  = blockIdx.x * TT + tx;
    const float* hb = h_in + (size_t)b * RC * T;

    // stage h tile and shifted tile (coalesced per k-row)
    #pragma unroll
    for (int i = 0; i < 16; ++i) {
        int k = y * 16 + i;
        sh_h[k][tx] = hb[(size_t)k * T + t];
        int ts = t - d;
        sh_s[k][tx] = (ts >= 0) ? hb[(size_t)k * T + ts] : 0.f;
    }
    __syncthreads();

    // conv: 16 (filt,gate) pairs per thread, k-loop unrolled by 2, float4 weight loads
    float accf[16], accg[16];
    #pragma unroll
    for (int i = 0; i < 16; ++i) {
        int c = y * 16 + i;
        accf[i] = db[c];
        accg[i] = db[c + RC];
    }
    for (int k = 0; k < RC; k += 2) {
        float hs0 = sh_s[k][tx],     hv0 = sh_h[k][tx];
        float hs1 = sh_s[k + 1][tx], hv1 = sh_h[k + 1][tx];
        #pragma unroll
        for (int i = 0; i < 16; ++i) {
            int c = y * 16 + i;
            // {W0[c][k], W1[c][k], W0[c][k+1], W1[c][k+1]}
            float4 wf = *(const float4*)&dw[((size_t)c * RC + k) * 2];
            float4 wg = *(const float4*)&dw[((size_t)(c + RC) * RC + k) * 2];
            accf[i] = fmaf(wf.x, hs0, fmaf(wf.y, hv0, fmaf(wf.z, hs1, fmaf(wf.w, hv1, accf[i]))));
            accg[i] = fmaf(wg.x, hs0, fmaf(wg.y, hv0, fmaf(wg.z, hs1, fmaf(wg.w, hv1, accg[i]))));
        }
    }

    // gated = tanh(filt) * sigmoid(gate)
    #pragma unroll
    for (int i = 0; i < 16; ++i) {
        int c = y * 16 + i;
        float e2 = __expf(-2.f * accf[i]);
        float th = (1.f - e2) * __builtin_amdgcn_rcpf(1.f + e2);
        float sg = __builtin_amdgcn_rcpf(1.f + __expf(-accg[i]));
        sh_g[c][tx] = th * sg;
    }
    __syncthreads();

    // res & skip 64x64 dots, k-loop unrolled by 4, float4 weight loads
    float racc[16], sacc[16];
    #pragma unroll
    for (int i = 0; i < 16; ++i) {
        int c = y * 16 + i;
        racc[i] = rb[c];
        sacc[i] = skb[c];
    }
    for (int k = 0; k < RC; k += 4) {
        float g0 = sh_g[k][tx],     g1 = sh_g[k + 1][tx];
        float g2 = sh_g[k + 2][tx], g3 = sh_g[k + 3][tx];
        #pragma unroll
        for (int i = 0; i < 16; ++i) {
            int c = y * 16 + i;
            float4 wr = *(const float4*)&rw[(size_t)c * RC + k];
            float4 wk = *(const float4*)&skw[(size_t)c * RC + k];
            racc[i] = fmaf(wr.x, g0, fmaf(wr.y, g1, fmaf(wr.z, g2, fmaf(wr.w, g3, racc[i]))));
            sacc[i] = fmaf(wk.x, g0, fmaf(wk.y, g1, fmaf(wk.z, g2, fmaf(wk.w, g3, sacc[i]))));
        }
    }

    // h_out = h + residual ; skip_sum (+)= skip
    #pragma unroll
    for (int i = 0; i < 16; ++i) {
        int c = y * 16 + i;
        h_out[((size_t)b * RC + c) * T + t] = sh_h[c][tx] + racc[i];
        size_t si = ((size_t)b * SC + c) * T + t;
        skip_sum[si] = accum ? (skip_sum[si] + sacc[i]) : sacc[i];
    }
}

// ---------------- end: out = end2( relu(end1(skip_sum)) ) ----------------
__global__ __launch_bounds__(256) void wn_end(
    const float* __restrict__ skip, const float* __restrict__ w1,
    const float* __restrict__ b1, const float* __restrict__ w2,
    const float* __restrict__ b2, float* __restrict__ out, int T)
{
    int t = blockIdx.x * blockDim.x + threadIdx.x;
    int b = blockIdx.y;
    float sv[SC];
    #pragma unroll
    for (int k = 0; k < SC; ++k)
        sv[k] = skip[((size_t)b * SC + k) * T + t];
    float acc = b2[0];
    for (int c = 0; c < SC; ++c) {
        float s = b1[c];
        #pragma unroll
        for (int k = 0; k < SC; k += 4) {
            float4 w = *(const float4*)&w1[(size_t)c * SC + k];
            s = fmaf(w.x, sv[k], fmaf(w.y, sv[k + 1], fmaf(w.z, sv[k + 2], fmaf(w.w, sv[k + 3], s))));
        }
        acc = fmaf(w2[c], fmaxf(s, 0.f), acc);
    }
    out[(size_t)b * T + t] = acc;
}

extern "C" void kernel_launch(void* const* d_in, const int* in_sizes, int n_in,
                              void* d_out, int out_size, void* d_ws, size_t ws_size,
                              hipStream_t stream)
{
    const float* x   = (const float*)d_in[0];
    const float* stw = (const float*)d_in[1];
    const float* stb = (const float*)d_in[2];
    const float* dw  = (const float*)d_in[3];
    const float* db  = (const float*)d_in[4];
    const float* rw  = (const float*)d_in[5];
    const float* rb  = (const float*)d_in[6];
    const float* skw = (const float*)d_in[7];
    const float* skb = (const float*)d_in[8];
    const float* e1w = (const float*)d_in[9];
    const float* e1b = (const float*)d_in[10];
    const float* e2w = (const float*)d_in[11];
    const float* e2b = (const float*)d_in[12];

    const int T = 32768;
    const int B = in_sizes[0] / T;

    float* h0 = (float*)d_ws;
    float* h1 = h0 + (size_t)B * RC * T;
    float* sk = h1 + (size_t)B * RC * T;

    wn_start<<<dim3(T / 256, B), 256, 0, stream>>>(x, stw, stb, h0, T);

    const float* hin = h0;
    float* hout = h1;
    for (int i = 0; i < NLAYERS; ++i) {
        int d = 1 << (i % 10);
        wn_layer<<<dim3(T / TT, B), dim3(64, 4), 0, stream>>>(
            hin, hout, sk,
            dw + (size_t)i * 2 * RC * RC * 2, db + (size_t)i * 2 * RC,
            rw + (size_t)i * RC * RC, rb + (size_t)i * RC,
            skw + (size_t)i * SC * RC, skb + (size_t)i * SC,
            d, T, i > 0 ? 1 : 0);
        const float* tmp = hout;
        hout = (float*)hin;
        hin = tmp;
    }

    wn_end<<<dim3(T / 256, B), 256, 0, stream>>>(sk, e1w, e1b, e2w, e2b, (float*)d_out, T);
}

// Round 6
// 1285.370 us; speedup vs baseline: 9.6652x; 9.6652x over previous
//
#include <hip/hip_runtime.h>
#include <hip/hip_bf16.h>

#define RC 64
#define SC 64
#define NLAYERS 30
#define TTILE 64

typedef __attribute__((ext_vector_type(8))) short bf16x8;
typedef __attribute__((ext_vector_type(4))) float f32x4;

__device__ __forceinline__ unsigned short f2bf(float f) {
    __hip_bfloat16 h = __float2bfloat16(f);
    return *reinterpret_cast<unsigned short*>(&h);
}
__device__ __forceinline__ float bf2f(unsigned short u) {
    unsigned int x = ((unsigned int)u) << 16;
    return *reinterpret_cast<float*>(&x);
}

// ---------- prep: gather weights into bf16 fragment-linear layout ----------
// W1 frags: f = w*8 + nf*4 + ks  (32 per layer), lane l, j=0..7:
//   c'' = w*32+nf*16+(l&15); b=c''>>4; c1 = (b&1?64:0)+(b>>1)*16+(c''&15)
//   k = ks*32+(l>>4)*8+j; tap = k<64?0:1 (tap0 = shifted input)
// W2 frags: f = w*4 + nf*2 + ks (16 per layer): res (nf=0) / skip (nf=1)
__global__ __launch_bounds__(256) void wn_prep(
    const float* __restrict__ dw, const float* __restrict__ rw,
    const float* __restrict__ skw, const float* __restrict__ db,
    const float* __restrict__ rb, const float* __restrict__ skb,
    unsigned short* __restrict__ pW1, unsigned short* __restrict__ pW2,
    float* __restrict__ pB1, float* __restrict__ pB2)
{
    const int i = blockIdx.x;
    const int tx = threadIdx.x;
    const int l = tx & 63;

    #pragma unroll
    for (int p = 0; p < 8; ++p) {
        int f = p * 4 + (tx >> 6);
        int w = f >> 3, nf = (f >> 2) & 1, ks = f & 3;
        int cpp = w * 32 + nf * 16 + (l & 15);
        int bb = cpp >> 4;
        int c1 = (bb & 1 ? 64 : 0) + (bb >> 1) * 16 + (cpp & 15);
        bf16x8 v;
        #pragma unroll
        for (int j = 0; j < 8; ++j) {
            int k = ks * 32 + (l >> 4) * 8 + j;
            int tap = (k < 64) ? 0 : 1;
            int kk = k & 63;
            v[j] = (short)f2bf(dw[(((size_t)i * 128 + c1) * 64 + kk) * 2 + tap]);
        }
        *(bf16x8*)&pW1[((size_t)(i * 32 + f) * 64 + l) * 8] = v;
    }

    #pragma unroll
    for (int p = 0; p < 4; ++p) {
        int f = p * 4 + (tx >> 6);
        int w = f >> 2, nf = (f >> 1) & 1, ks = f & 1;
        int cpp = w * 32 + nf * 16 + (l & 15);
        int bb = cpp >> 4;
        int c2 = (bb >> 1) * 16 + (cpp & 15);
        const float* src = (bb & 1) ? skw : rw;
        bf16x8 v;
        #pragma unroll
        for (int j = 0; j < 8; ++j) {
            int k = ks * 32 + (l >> 4) * 8 + j;
            v[j] = (short)f2bf(src[((size_t)i * 64 + c2) * 64 + k]);
        }
        *(bf16x8*)&pW2[((size_t)(i * 16 + f) * 64 + l) * 8] = v;
    }

    if (tx < 128) {
        int bb = tx >> 4, r = tx & 15;
        int c1 = (bb & 1 ? 64 : 0) + (bb >> 1) * 16 + r;
        pB1[i * 128 + tx] = db[i * 128 + c1];
        int c2 = (bb >> 1) * 16 + r;
        pB2[i * 128 + tx] = (bb & 1) ? skb[i * 64 + c2] : rb[i * 64 + c2];
    }
}

// ---------- start: h[b][t][c] fp32 t-major ----------
__global__ __launch_bounds__(256) void wn_start(
    const float* __restrict__ x, const float* __restrict__ sw,
    const float* __restrict__ sb, float* __restrict__ h, int T)
{
    int t = blockIdx.x * blockDim.x + threadIdx.x;
    int b = blockIdx.y;
    float xv = x[(size_t)b * T + t];
    float* row = h + ((size_t)b * T + t) * 64;
    #pragma unroll
    for (int c = 0; c < 64; c += 4) {
        float4 v;
        v.x = fmaf(sw[c], xv, sb[c]);
        v.y = fmaf(sw[c + 1], xv, sb[c + 1]);
        v.z = fmaf(sw[c + 2], xv, sb[c + 2]);
        v.w = fmaf(sw[c + 3], xv, sb[c + 3]);
        *(float4*)&row[c] = v;
    }
}

// ---------- fused layer: MFMA conv + gate + MFMA res/skip ----------
// block 256 = 4 waves; tile = 64 t. Wave w owns conv cols c''=[32w,32w+32).
__global__ __launch_bounds__(256) void wn_layer(
    const float* __restrict__ h_in, float* __restrict__ h_out,
    float* __restrict__ skip_sum,
    const unsigned short* __restrict__ pW1, const unsigned short* __restrict__ pW2,
    const float* __restrict__ pB1, const float* __restrict__ pB2,
    int d, int T, int accum)
{
    __shared__ unsigned short Xs[64 * 128];  // [t][128k] bf16, XOR-swizzled, 16KB
    __shared__ unsigned short Gs[64 * 64];   // [t][64c]  bf16, XOR-swizzled, 8KB

    const int tx = threadIdx.x;
    const int w = tx >> 6;
    const int l = tx & 63;
    const int lr = l & 15;   // row/col-within-frag index
    const int lg = l >> 4;   // k-group
    const int b = blockIdx.y;
    const int t0 = blockIdx.x * TTILE;
    const size_t bT = (size_t)b * T;

    // ---- stage X = [h(t-d) || h(t)] as bf16, fp32 source ----
    #pragma unroll
    for (int q = 0; q < 4; ++q) {
        int idx = tx * 4 + q;          // 0..1023 16B-chunks
        int t = idx >> 4;
        int ch = idx & 15;             // chunk: 0-7 shifted half, 8-15 current half
        int tt = (ch < 8) ? (t0 + t - d) : (t0 + t);
        bf16x8 v;
        if (tt >= 0) {
            const float4* s4 = (const float4*)(h_in + ((size_t)(bT + tt)) * 64 + (ch & 7) * 8);
            float4 a = s4[0], c4 = s4[1];
            v[0] = (short)f2bf(a.x);  v[1] = (short)f2bf(a.y);
            v[2] = (short)f2bf(a.z);  v[3] = (short)f2bf(a.w);
            v[4] = (short)f2bf(c4.x); v[5] = (short)f2bf(c4.y);
            v[6] = (short)f2bf(c4.z); v[7] = (short)f2bf(c4.w);
        } else {
            #pragma unroll
            for (int j = 0; j < 8; ++j) v[j] = 0;
        }
        int swz = (ch & 8) | ((ch & 7) ^ (t & 7));
        *(bf16x8*)&Xs[(t * 256 + swz * 16) >> 1] = v;
    }

    // ---- load weight fragments (coalesced b128, loop-invariant) ----
    bf16x8 W1f[2][4];
    #pragma unroll
    for (int nf = 0; nf < 2; ++nf)
        #pragma unroll
        for (int ks = 0; ks < 4; ++ks) {
            int f = w * 8 + nf * 4 + ks;
            W1f[nf][ks] = *(const bf16x8*)&pW1[((size_t)f * 64 + l) * 8];
        }
    bf16x8 W2f[2][2];
    #pragma unroll
    for (int nf = 0; nf < 2; ++nf)
        #pragma unroll
        for (int ks = 0; ks < 2; ++ks) {
            int f = w * 4 + nf * 2 + ks;
            W2f[nf][ks] = *(const bf16x8*)&pW2[((size_t)f * 64 + l) * 8];
        }

    float bias1[2], bias2[2];
    #pragma unroll
    for (int nf = 0; nf < 2; ++nf) {
        bias1[nf] = pB1[w * 32 + nf * 16 + lr];
        bias2[nf] = pB2[w * 32 + nf * 16 + lr];
    }

    __syncthreads();

    // ---- GEMM1: D1[t][c''] = X[t][k] * W1^T[k][c''] ----
    f32x4 acc1[4][2];
    #pragma unroll
    for (int mf = 0; mf < 4; ++mf) {
        #pragma unroll
        for (int nf = 0; nf < 2; ++nf) {
            f32x4 a = {bias1[nf], bias1[nf], bias1[nf], bias1[nf]};
            #pragma unroll
            for (int ks = 0; ks < 4; ++ks) {
                int tr = mf * 16 + lr;
                int chunk = ks * 4 + lg;
                int swz = (chunk & 8) | ((chunk & 7) ^ (tr & 7));
                bf16x8 av = *(const bf16x8*)&Xs[(tr * 256 + swz * 16) >> 1];
                a = __builtin_amdgcn_mfma_f32_16x16x32_bf16(av, W1f[nf][ks], a, 0, 0, 0);
            }
            acc1[mf][nf] = a;
        }
    }

    // ---- gate: lane-local (filt,gate) pair; write gated tile to LDS ----
    const int gc = w * 16 + lr;            // gated channel 0..63
    #pragma unroll
    for (int mf = 0; mf < 4; ++mf) {
        #pragma unroll
        for (int r = 0; r < 4; ++r) {
            int tr = mf * 16 + lg * 4 + r;
            float fv = fminf(fmaxf(acc1[mf][0][r], -30.f), 30.f);
            float gv = fminf(fmaxf(acc1[mf][1][r], -30.f), 30.f);
            float e2 = __expf(-2.f * fv);
            float th = (1.f - e2) * __builtin_amdgcn_rcpf(1.f + e2);
            float sg = __builtin_amdgcn_rcpf(1.f + __expf(-gv));
            float gated = th * sg;
            int byte = tr * 128 + (((gc >> 3) ^ (tr & 7)) * 16) + (gc & 7) * 2;
            Gs[byte >> 1] = f2bf(gated);
        }
    }

    __syncthreads();

    // ---- GEMM2: D2[t][c2''] = G[t][c] * W2^T[c][c2''] ----
    f32x4 acc2[4][2];
    #pragma unroll
    for (int mf = 0; mf < 4; ++mf) {
        #pragma unroll
        for (int nf = 0; nf < 2; ++nf) {
            f32x4 a = {bias2[nf], bias2[nf], bias2[nf], bias2[nf]};
            #pragma unroll
            for (int ks = 0; ks < 2; ++ks) {
                int tr = mf * 16 + lr;
                int chunk = ks * 4 + lg;
                int swz = chunk ^ (tr & 7);
                bf16x8 av = *(const bf16x8*)&Gs[(tr * 128 + swz * 16) >> 1];
                a = __builtin_amdgcn_mfma_f32_16x16x32_bf16(av, W2f[nf][ks], a, 0, 0, 0);
            }
            acc2[mf][nf] = a;
        }
    }

    // ---- epilogue: h_out = h + res (fp32 chain), skip_sum (+)= skip ----
    #pragma unroll
    for (int mf = 0; mf < 4; ++mf) {
        #pragma unroll
        for (int r = 0; r < 4; ++r) {
            int tr = mf * 16 + lg * 4 + r;
            size_t gidx = (bT + t0 + tr) * 64 + gc;
            h_out[gidx] = h_in[gidx] + acc2[mf][0][r];
            float s = acc2[mf][1][r];
            skip_sum[gidx] = accum ? (skip_sum[gidx] + s) : s;
        }
    }
}

// ---------- end: out = end2( relu(end1(skip_sum)) ) ----------
__global__ __launch_bounds__(256) void wn_end(
    const float* __restrict__ skip, const float* __restrict__ w1,
    const float* __restrict__ b1, const float* __restrict__ w2,
    const float* __restrict__ b2, float* __restrict__ out, int T)
{
    int t = blockIdx.x * blockDim.x + threadIdx.x;
    int b = blockIdx.y;
    const float* row = skip + ((size_t)b * T + t) * 64;
    float sv[SC];
    #pragma unroll
    for (int k = 0; k < SC; k += 4) {
        float4 v = *(const float4*)&row[k];
        sv[k] = v.x; sv[k + 1] = v.y; sv[k + 2] = v.z; sv[k + 3] = v.w;
    }
    float acc = b2[0];
    for (int c = 0; c < SC; ++c) {
        float s = b1[c];
        #pragma unroll
        for (int k = 0; k < SC; k += 4) {
            float4 wv = *(const float4*)&w1[(size_t)c * SC + k];
            s = fmaf(wv.x, sv[k], fmaf(wv.y, sv[k + 1], fmaf(wv.z, sv[k + 2], fmaf(wv.w, sv[k + 3], s))));
        }
        acc = fmaf(w2[c], fmaxf(s, 0.f), acc);
    }
    out[(size_t)b * T + t] = acc;
}

extern "C" void kernel_launch(void* const* d_in, const int* in_sizes, int n_in,
                              void* d_out, int out_size, void* d_ws, size_t ws_size,
                              hipStream_t stream)
{
    const float* x   = (const float*)d_in[0];
    const float* stw = (const float*)d_in[1];
    const float* stb = (const float*)d_in[2];
    const float* dw  = (const float*)d_in[3];
    const float* db  = (const float*)d_in[4];
    const float* rw  = (const float*)d_in[5];
    const float* rb  = (const float*)d_in[6];
    const float* skw = (const float*)d_in[7];
    const float* skb = (const float*)d_in[8];
    const float* e1w = (const float*)d_in[9];
    const float* e1b = (const float*)d_in[10];
    const float* e2w = (const float*)d_in[11];
    const float* e2b = (const float*)d_in[12];

    const int T = 32768;
    const int B = in_sizes[0] / T;

    char* ws = (char*)d_ws;
    const size_t hbytes = (size_t)B * T * 64 * 4;      // 33.5 MB fp32
    float* h0 = (float*)ws;
    float* h1 = (float*)(ws + hbytes);
    float* sk = (float*)(ws + 2 * hbytes);
    unsigned short* pW1 = (unsigned short*)(ws + 3 * hbytes);
    unsigned short* pW2 = pW1 + (size_t)NLAYERS * 32 * 64 * 8;
    float* pB1 = (float*)(pW2 + (size_t)NLAYERS * 16 * 64 * 8);
    float* pB2 = pB1 + NLAYERS * 128;

    wn_prep<<<dim3(NLAYERS), 256, 0, stream>>>(dw, rw, skw, db, rb, skb, pW1, pW2, pB1, pB2);
    wn_start<<<dim3(T / 256, B), 256, 0, stream>>>(x, stw, stb, h0, T);

    const float* hin = h0;
    float* hout = h1;
    for (int i = 0; i < NLAYERS; ++i) {
        int d = 1 << (i % 10);
        wn_layer<<<dim3(T / TTILE, B), 256, 0, stream>>>(
            hin, hout, sk,
            pW1 + (size_t)i * 32 * 64 * 8, pW2 + (size_t)i * 16 * 64 * 8,
            pB1 + i * 128, pB2 + i * 128,
            d, T, i > 0 ? 1 : 0);
        const float* tmp = hout;
        hout = (float*)hin;
        hin = tmp;
    }

    wn_end<<<dim3(T / 256, B), 256, 0, stream>>>(sk, e1w, e1b, e2w, e2b, (float*)d_out, T);
}

// Round 8
// 1285.015 us; speedup vs baseline: 9.6679x; 1.0003x over previous
//
#include <hip/hip_runtime.h>
#include <hip/hip_bf16.h>
#include <hip/hip_cooperative_groups.h>

namespace cg = cooperative_groups;

#define RC 64
#define SC 64
#define NLAYERS 30
#define TTILE 64

typedef __attribute__((ext_vector_type(8))) short bf16x8;
typedef __attribute__((ext_vector_type(4))) float f32x4;

__device__ __forceinline__ unsigned short f2bf(float f) {
    __hip_bfloat16 h = __float2bfloat16(f);
    return *reinterpret_cast<unsigned short*>(&h);
}

// ---------- prep: gather weights into bf16 fragment-linear layout (verified) ----------
__global__ __launch_bounds__(256) void wn_prep(
    const float* __restrict__ dw, const float* __restrict__ rw,
    const float* __restrict__ skw, const float* __restrict__ db,
    const float* __restrict__ rb, const float* __restrict__ skb,
    unsigned short* __restrict__ pW1, unsigned short* __restrict__ pW2,
    float* __restrict__ pB1, float* __restrict__ pB2)
{
    const int i = blockIdx.x;
    const int tx = threadIdx.x;
    const int l = tx & 63;

    #pragma unroll
    for (int p = 0; p < 8; ++p) {
        int f = p * 4 + (tx >> 6);
        int w = f >> 3, nf = (f >> 2) & 1, ks = f & 3;
        int cpp = w * 32 + nf * 16 + (l & 15);
        int bb = cpp >> 4;
        int c1 = (bb & 1 ? 64 : 0) + (bb >> 1) * 16 + (cpp & 15);
        bf16x8 v;
        #pragma unroll
        for (int j = 0; j < 8; ++j) {
            int k = ks * 32 + (l >> 4) * 8 + j;
            int tap = (k < 64) ? 0 : 1;
            int kk = k & 63;
            v[j] = (short)f2bf(dw[(((size_t)i * 128 + c1) * 64 + kk) * 2 + tap]);
        }
        *(bf16x8*)&pW1[((size_t)(i * 32 + f) * 64 + l) * 8] = v;
    }

    #pragma unroll
    for (int p = 0; p < 4; ++p) {
        int f = p * 4 + (tx >> 6);
        int w = f >> 2, nf = (f >> 1) & 1, ks = f & 1;
        int cpp = w * 32 + nf * 16 + (l & 15);
        int bb = cpp >> 4;
        int c2 = (bb >> 1) * 16 + (cpp & 15);
        const float* src = (bb & 1) ? skw : rw;
        bf16x8 v;
        #pragma unroll
        for (int j = 0; j < 8; ++j) {
            int k = ks * 32 + (l >> 4) * 8 + j;
            v[j] = (short)f2bf(src[((size_t)i * 64 + c2) * 64 + k]);
        }
        *(bf16x8*)&pW2[((size_t)(i * 16 + f) * 64 + l) * 8] = v;
    }

    if (tx < 128) {
        int bb = tx >> 4, r = tx & 15;
        int c1 = (bb & 1 ? 64 : 0) + (bb >> 1) * 16 + r;
        pB1[i * 128 + tx] = db[i * 128 + c1];
        int c2 = (bb >> 1) * 16 + r;
        pB2[i * 128 + tx] = (bb & 1) ? skb[i * 64 + c2] : rb[i * 64 + c2];
    }
}

// ---------- start: h[b][t][c] fp32 t-major ----------
__global__ __launch_bounds__(256) void wn_start(
    const float* __restrict__ x, const float* __restrict__ sw,
    const float* __restrict__ sb, float* __restrict__ h, int T)
{
    int t = blockIdx.x * blockDim.x + threadIdx.x;
    int b = blockIdx.y;
    float xv = x[(size_t)b * T + t];
    float* row = h + ((size_t)b * T + t) * 64;
    #pragma unroll
    for (int c = 0; c < 64; c += 4) {
        float4 v;
        v.x = fmaf(sw[c], xv, sb[c]);
        v.y = fmaf(sw[c + 1], xv, sb[c + 1]);
        v.z = fmaf(sw[c + 2], xv, sb[c + 2]);
        v.w = fmaf(sw[c + 3], xv, sb[c + 3]);
        *(float4*)&row[c] = v;
    }
}

// ---------- per-layer kernel (round-6 VERIFIED; fallback path) ----------
__global__ __launch_bounds__(256) void wn_layer(
    const float* __restrict__ h_in, float* __restrict__ h_out,
    float* __restrict__ skip_sum,
    const unsigned short* __restrict__ pW1, const unsigned short* __restrict__ pW2,
    const float* __restrict__ pB1, const float* __restrict__ pB2,
    int d, int T, int accum)
{
    __shared__ unsigned short Xs[64 * 128];
    __shared__ unsigned short Gs[64 * 64];

    const int tx = threadIdx.x;
    const int w = tx >> 6;
    const int l = tx & 63;
    const int lr = l & 15;
    const int lg = l >> 4;
    const int b = blockIdx.y;
    const int t0 = blockIdx.x * TTILE;
    const size_t bT = (size_t)b * T;

    #pragma unroll
    for (int q = 0; q < 4; ++q) {
        int idx = tx * 4 + q;
        int t = idx >> 4;
        int ch = idx & 15;
        int tt = (ch < 8) ? (t0 + t - d) : (t0 + t);
        bf16x8 v;
        if (tt >= 0) {
            const float4* s4 = (const float4*)(h_in + ((size_t)(bT + tt)) * 64 + (ch & 7) * 8);
            float4 a = s4[0], c4 = s4[1];
            v[0] = (short)f2bf(a.x);  v[1] = (short)f2bf(a.y);
            v[2] = (short)f2bf(a.z);  v[3] = (short)f2bf(a.w);
            v[4] = (short)f2bf(c4.x); v[5] = (short)f2bf(c4.y);
            v[6] = (short)f2bf(c4.z); v[7] = (short)f2bf(c4.w);
        } else {
            #pragma unroll
            for (int j = 0; j < 8; ++j) v[j] = 0;
        }
        int swz = (ch & 8) | ((ch & 7) ^ (t & 7));
        *(bf16x8*)&Xs[(t * 256 + swz * 16) >> 1] = v;
    }

    bf16x8 W1f[2][4];
    #pragma unroll
    for (int nf = 0; nf < 2; ++nf)
        #pragma unroll
        for (int ks = 0; ks < 4; ++ks)
            W1f[nf][ks] = *(const bf16x8*)&pW1[((size_t)(w * 8 + nf * 4 + ks) * 64 + l) * 8];
    bf16x8 W2f[2][2];
    #pragma unroll
    for (int nf = 0; nf < 2; ++nf)
        #pragma unroll
        for (int ks = 0; ks < 2; ++ks)
            W2f[nf][ks] = *(const bf16x8*)&pW2[((size_t)(w * 4 + nf * 2 + ks) * 64 + l) * 8];

    float bias1[2], bias2[2];
    #pragma unroll
    for (int nf = 0; nf < 2; ++nf) {
        bias1[nf] = pB1[w * 32 + nf * 16 + lr];
        bias2[nf] = pB2[w * 32 + nf * 16 + lr];
    }

    __syncthreads();

    f32x4 acc1[4][2];
    #pragma unroll
    for (int mf = 0; mf < 4; ++mf) {
        #pragma unroll
        for (int nf = 0; nf < 2; ++nf) {
            f32x4 a = {bias1[nf], bias1[nf], bias1[nf], bias1[nf]};
            #pragma unroll
            for (int ks = 0; ks < 4; ++ks) {
                int tr = mf * 16 + lr;
                int chunk = ks * 4 + lg;
                int swz = (chunk & 8) | ((chunk & 7) ^ (tr & 7));
                bf16x8 av = *(const bf16x8*)&Xs[(tr * 256 + swz * 16) >> 1];
                a = __builtin_amdgcn_mfma_f32_16x16x32_bf16(av, W1f[nf][ks], a, 0, 0, 0);
            }
            acc1[mf][nf] = a;
        }
    }

    const int gc = w * 16 + lr;
    #pragma unroll
    for (int mf = 0; mf < 4; ++mf) {
        #pragma unroll
        for (int r = 0; r < 4; ++r) {
            int tr = mf * 16 + lg * 4 + r;
            float fv = fminf(fmaxf(acc1[mf][0][r], -30.f), 30.f);
            float gv = fminf(fmaxf(acc1[mf][1][r], -30.f), 30.f);
            float e2 = __expf(-2.f * fv);
            float th = (1.f - e2) * __builtin_amdgcn_rcpf(1.f + e2);
            float sg = __builtin_amdgcn_rcpf(1.f + __expf(-gv));
            float gated = th * sg;
            int byte = tr * 128 + (((gc >> 3) ^ (tr & 7)) * 16) + (gc & 7) * 2;
            Gs[byte >> 1] = f2bf(gated);
        }
    }

    __syncthreads();

    f32x4 acc2[4][2];
    #pragma unroll
    for (int mf = 0; mf < 4; ++mf) {
        #pragma unroll
        for (int nf = 0; nf < 2; ++nf) {
            f32x4 a = {bias2[nf], bias2[nf], bias2[nf], bias2[nf]};
            #pragma unroll
            for (int ks = 0; ks < 2; ++ks) {
                int tr = mf * 16 + lr;
                int chunk = ks * 4 + lg;
                int swz = chunk ^ (tr & 7);
                bf16x8 av = *(const bf16x8*)&Gs[(tr * 128 + swz * 16) >> 1];
                a = __builtin_amdgcn_mfma_f32_16x16x32_bf16(av, W2f[nf][ks], a, 0, 0, 0);
            }
            acc2[mf][nf] = a;
        }
    }

    #pragma unroll
    for (int mf = 0; mf < 4; ++mf) {
        #pragma unroll
        for (int r = 0; r < 4; ++r) {
            int tr = mf * 16 + lg * 4 + r;
            size_t gidx = (bT + t0 + tr) * 64 + gc;
            h_out[gidx] = h_in[gidx] + acc2[mf][0][r];
            float s = acc2[mf][1][r];
            skip_sum[gidx] = accum ? (skip_sum[gidx] + s) : s;
        }
    }
}

// ---------- persistent cooperative kernel, templated on tiles/block ----------
template<int NT, int MINW>
__global__ __launch_bounds__(256, MINW) void wn_fused(
    float* __restrict__ hA, float* __restrict__ hB,
    float* __restrict__ sk,
    const unsigned short* __restrict__ pW1, const unsigned short* __restrict__ pW2,
    const float* __restrict__ pB1, const float* __restrict__ pB2,
    int T)
{
    cg::grid_group grid = cg::this_grid();
    __shared__ unsigned short Xs[64 * 128];
    __shared__ unsigned short Gs[64 * 64];

    const int tx = threadIdx.x;
    const int w = tx >> 6;
    const int l = tx & 63;
    const int lr = l & 15;
    const int lg = l >> 4;
    const int bid = blockIdx.x;
    const int tpb = T >> 6;
    const int gc = w * 16 + lr;

    float sacc[NT][16];
    #pragma unroll
    for (int j = 0; j < NT; ++j)
        #pragma unroll
        for (int i = 0; i < 16; ++i) sacc[j][i] = 0.f;

    const float* hin = hA;
    float* hout = hB;

    for (int layer = 0; layer < NLAYERS; ++layer) {
        const int d = 1 << (layer % 10);
        const unsigned short* W1p = pW1 + (size_t)layer * 32 * 64 * 8;
        const unsigned short* W2p = pW2 + (size_t)layer * 16 * 64 * 8;

        bf16x8 W1f[2][4];
        #pragma unroll
        for (int nf = 0; nf < 2; ++nf)
            #pragma unroll
            for (int ks = 0; ks < 4; ++ks)
                W1f[nf][ks] = *(const bf16x8*)&W1p[((size_t)(w * 8 + nf * 4 + ks) * 64 + l) * 8];
        bf16x8 W2f[2][2];
        #pragma unroll
        for (int nf = 0; nf < 2; ++nf)
            #pragma unroll
            for (int ks = 0; ks < 2; ++ks)
                W2f[nf][ks] = *(const bf16x8*)&W2p[((size_t)(w * 4 + nf * 2 + ks) * 64 + l) * 8];
        float bias1[2], bias2[2];
        #pragma unroll
        for (int nf = 0; nf < 2; ++nf) {
            bias1[nf] = pB1[layer * 128 + w * 32 + nf * 16 + lr];
            bias2[nf] = pB2[layer * 128 + w * 32 + nf * 16 + lr];
        }

        #pragma unroll
        for (int j = 0; j < NT; ++j) {
            const int tile = bid * NT + j;
            const int b = tile / tpb;
            const int t0 = (tile - b * tpb) * 64;
            const size_t bT = (size_t)b * T;

            __syncthreads();

            #pragma unroll
            for (int q = 0; q < 4; ++q) {
                int idx = tx * 4 + q;
                int t = idx >> 4;
                int ch = idx & 15;
                int tt = (ch < 8) ? (t0 + t - d) : (t0 + t);
                bf16x8 v;
                if (tt >= 0) {
                    const float4* s4 = (const float4*)(hin + ((size_t)(bT + tt)) * 64 + (ch & 7) * 8);
                    float4 a = s4[0], c4 = s4[1];
                    v[0] = (short)f2bf(a.x);  v[1] = (short)f2bf(a.y);
                    v[2] = (short)f2bf(a.z);  v[3] = (short)f2bf(a.w);
                    v[4] = (short)f2bf(c4.x); v[5] = (short)f2bf(c4.y);
                    v[6] = (short)f2bf(c4.z); v[7] = (short)f2bf(c4.w);
                } else {
                    #pragma unroll
                    for (int jj = 0; jj < 8; ++jj) v[jj] = 0;
                }
                int swz = (ch & 8) | ((ch & 7) ^ (t & 7));
                *(bf16x8*)&Xs[(t * 256 + swz * 16) >> 1] = v;
            }
            __syncthreads();

            f32x4 acc1[4][2];
            #pragma unroll
            for (int mf = 0; mf < 4; ++mf) {
                #pragma unroll
                for (int nf = 0; nf < 2; ++nf) {
                    f32x4 a = {bias1[nf], bias1[nf], bias1[nf], bias1[nf]};
                    #pragma unroll
                    for (int ks = 0; ks < 4; ++ks) {
                        int tr = mf * 16 + lr;
                        int chunk = ks * 4 + lg;
                        int swz = (chunk & 8) | ((chunk & 7) ^ (tr & 7));
                        bf16x8 av = *(const bf16x8*)&Xs[(tr * 256 + swz * 16) >> 1];
                        a = __builtin_amdgcn_mfma_f32_16x16x32_bf16(av, W1f[nf][ks], a, 0, 0, 0);
                    }
                    acc1[mf][nf] = a;
                }
            }

            #pragma unroll
            for (int mf = 0; mf < 4; ++mf) {
                #pragma unroll
                for (int r = 0; r < 4; ++r) {
                    int tr = mf * 16 + lg * 4 + r;
                    float fv = fminf(fmaxf(acc1[mf][0][r], -30.f), 30.f);
                    float gv = fminf(fmaxf(acc1[mf][1][r], -30.f), 30.f);
                    float e2 = __expf(-2.f * fv);
                    float th = (1.f - e2) * __builtin_amdgcn_rcpf(1.f + e2);
                    float sg = __builtin_amdgcn_rcpf(1.f + __expf(-gv));
                    float gated = th * sg;
                    int byte = tr * 128 + (((gc >> 3) ^ (tr & 7)) * 16) + (gc & 7) * 2;
                    Gs[byte >> 1] = f2bf(gated);
                }
            }
            __syncthreads();

            f32x4 acc2[4][2];
            #pragma unroll
            for (int mf = 0; mf < 4; ++mf) {
                #pragma unroll
                for (int nf = 0; nf < 2; ++nf) {
                    f32x4 a = {bias2[nf], bias2[nf], bias2[nf], bias2[nf]};
                    #pragma unroll
                    for (int ks = 0; ks < 2; ++ks) {
                        int tr = mf * 16 + lr;
                        int chunk = ks * 4 + lg;
                        int swz = chunk ^ (tr & 7);
                        bf16x8 av = *(const bf16x8*)&Gs[(tr * 128 + swz * 16) >> 1];
                        a = __builtin_amdgcn_mfma_f32_16x16x32_bf16(av, W2f[nf][ks], a, 0, 0, 0);
                    }
                    acc2[mf][nf] = a;
                }
            }

            #pragma unroll
            for (int mf = 0; mf < 4; ++mf) {
                #pragma unroll
                for (int r = 0; r < 4; ++r) {
                    int tr = mf * 16 + lg * 4 + r;
                    size_t gidx = (bT + t0 + tr) * 64 + gc;
                    hout[gidx] = hin[gidx] + acc2[mf][0][r];
                    sacc[j][mf * 4 + r] += acc2[mf][1][r];
                }
            }
        }

        grid.sync();
        float* tmp = hout;
        hout = (float*)hin;
        hin = tmp;
    }

    #pragma unroll
    for (int j = 0; j < NT; ++j) {
        const int tile = bid * NT + j;
        const int b = tile / tpb;
        const int t0 = (tile - b * tpb) * 64;
        const size_t bT = (size_t)b * T;
        #pragma unroll
        for (int mf = 0; mf < 4; ++mf) {
            #pragma unroll
            for (int r = 0; r < 4; ++r) {
                int tr = mf * 16 + lg * 4 + r;
                sk[(bT + t0 + tr) * 64 + gc] = sacc[j][mf * 4 + r];
            }
        }
    }
}

// ---------- end: out = end2( relu(end1(skip_sum)) ) ----------
__global__ __launch_bounds__(256) void wn_end(
    const float* __restrict__ skip, const float* __restrict__ w1,
    const float* __restrict__ b1, const float* __restrict__ w2,
    const float* __restrict__ b2, float* __restrict__ out, int T)
{
    int t = blockIdx.x * blockDim.x + threadIdx.x;
    int b = blockIdx.y;
    const float* row = skip + ((size_t)b * T + t) * 64;
    float sv[SC];
    #pragma unroll
    for (int k = 0; k < SC; k += 4) {
        float4 v = *(const float4*)&row[k];
        sv[k] = v.x; sv[k + 1] = v.y; sv[k + 2] = v.z; sv[k + 3] = v.w;
    }
    float acc = b2[0];
    for (int c = 0; c < SC; ++c) {
        float s = b1[c];
        #pragma unroll
        for (int k = 0; k < SC; k += 4) {
            float4 wv = *(const float4*)&w1[(size_t)c * SC + k];
            s = fmaf(wv.x, sv[k], fmaf(wv.y, sv[k + 1], fmaf(wv.z, sv[k + 2], fmaf(wv.w, sv[k + 3], s))));
        }
        acc = fmaf(w2[c], fmaxf(s, 0.f), acc);
    }
    out[(size_t)b * T + t] = acc;
}

extern "C" void kernel_launch(void* const* d_in, const int* in_sizes, int n_in,
                              void* d_out, int out_size, void* d_ws, size_t ws_size,
                              hipStream_t stream)
{
    const float* x   = (const float*)d_in[0];
    const float* stw = (const float*)d_in[1];
    const float* stb = (const float*)d_in[2];
    const float* dw  = (const float*)d_in[3];
    const float* db  = (const float*)d_in[4];
    const float* rw  = (const float*)d_in[5];
    const float* rb  = (const float*)d_in[6];
    const float* skw = (const float*)d_in[7];
    const float* skb = (const float*)d_in[8];
    const float* e1w = (const float*)d_in[9];
    const float* e1b = (const float*)d_in[10];
    const float* e2w = (const float*)d_in[11];
    const float* e2b = (const float*)d_in[12];

    const int T = 32768;
    const int B = in_sizes[0] / T;

    char* ws = (char*)d_ws;
    const size_t hbytes = (size_t)B * T * 64 * 4;
    float* h0 = (float*)ws;
    float* h1 = (float*)(ws + hbytes);
    float* sk = (float*)(ws + 2 * hbytes);
    unsigned short* pW1 = (unsigned short*)(ws + 3 * hbytes);
    unsigned short* pW2 = pW1 + (size_t)NLAYERS * 32 * 64 * 8;
    float* pB1 = (float*)(pW2 + (size_t)NLAYERS * 16 * 64 * 8);
    float* pB2 = pB1 + NLAYERS * 128;

    wn_prep<<<dim3(NLAYERS), 256, 0, stream>>>(dw, rw, skw, db, rb, skb, pW1, pW2, pB1, pB2);
    wn_start<<<dim3(T / 256, B), 256, 0, stream>>>(x, stw, stb, h0, T);

    const int NCU = 256;                  // gfx950 / MI355X
    int ntiles = B * (T >> 6);            // 2048
    int Tval = T;
    void* args[] = { (void*)&h0, (void*)&h1, (void*)&sk,
                     (void*)&pW1, (void*)&pW2, (void*)&pB1, (void*)&pB2,
                     (void*)&Tval };

    // Pick the largest cooperative grid that provably fits (host-only queries,
    // graph-capture safe); verify the launch return code; else fall back to the
    // verified per-layer chain.
    bool launched = false;
    int occ2 = 0, occ4 = 0;
    (void)hipOccupancyMaxActiveBlocksPerMultiprocessor(&occ2, wn_fused<2, 4>, 256, 0);
    (void)hipOccupancyMaxActiveBlocksPerMultiprocessor(&occ4, wn_fused<4, 2>, 256, 0);

    if (occ2 * NCU >= ntiles / 2) {
        hipError_t e = hipLaunchCooperativeKernel((void*)wn_fused<2, 4>,
                                                  dim3(ntiles / 2), dim3(256), args, 0, stream);
        launched = (e == hipSuccess);
    }
    if (!launched && occ4 * NCU >= ntiles / 4) {
        hipError_t e = hipLaunchCooperativeKernel((void*)wn_fused<4, 2>,
                                                  dim3(ntiles / 4), dim3(256), args, 0, stream);
        launched = (e == hipSuccess);
    }

    if (!launched) {
        // verified round-6 per-layer chain
        const float* hin = h0;
        float* hout = h1;
        for (int i = 0; i < NLAYERS; ++i) {
            int d = 1 << (i % 10);
            wn_layer<<<dim3(T / TTILE, B), 256, 0, stream>>>(
                hin, hout, sk,
                pW1 + (size_t)i * 32 * 64 * 8, pW2 + (size_t)i * 16 * 64 * 8,
                pB1 + i * 128, pB2 + i * 128,
                d, T, i > 0 ? 1 : 0);
            const float* tmp = hout;
            hout = (float*)hin;
            hin = tmp;
        }
    }

    wn_end<<<dim3(T / 256, B), 256, 0, stream>>>(sk, e1w, e1b, e2w, e2b, (float*)d_out, T);
}

// Round 12
// 743.233 us; speedup vs baseline: 16.7153x; 1.7290x over previous
//
#include <hip/hip_runtime.h>
#include <hip/hip_bf16.h>

#define RC 64
#define SC 64
#define NLAYERS 30
#define TTILE 64

typedef __attribute__((ext_vector_type(8))) short bf16x8;
typedef __attribute__((ext_vector_type(4))) float f32x4;

__device__ __forceinline__ unsigned short f2bf(float f) {
    __hip_bfloat16 h = __float2bfloat16(f);
    return *reinterpret_cast<unsigned short*>(&h);
}
__device__ __forceinline__ float bf2f(unsigned short u) {
    unsigned int x = ((unsigned int)u) << 16;
    return *reinterpret_cast<float*>(&x);
}

// ---------- prep: gather weights into bf16 fragment-linear layout (verified r6) ----------
__global__ __launch_bounds__(256) void wn_prep(
    const float* __restrict__ dw, const float* __restrict__ rw,
    const float* __restrict__ skw, const float* __restrict__ db,
    const float* __restrict__ rb, const float* __restrict__ skb,
    unsigned short* __restrict__ pW1, unsigned short* __restrict__ pW2,
    float* __restrict__ pB1, float* __restrict__ pB2)
{
    const int i = blockIdx.x;
    const int tx = threadIdx.x;
    const int l = tx & 63;

    #pragma unroll
    for (int p = 0; p < 8; ++p) {
        int f = p * 4 + (tx >> 6);
        int w = f >> 3, nf = (f >> 2) & 1, ks = f & 3;
        int cpp = w * 32 + nf * 16 + (l & 15);
        int bb = cpp >> 4;
        int c1 = (bb & 1 ? 64 : 0) + (bb >> 1) * 16 + (cpp & 15);
        bf16x8 v;
        #pragma unroll
        for (int j = 0; j < 8; ++j) {
            int k = ks * 32 + (l >> 4) * 8 + j;
            int tap = (k < 64) ? 0 : 1;
            int kk = k & 63;
            v[j] = (short)f2bf(dw[(((size_t)i * 128 + c1) * 64 + kk) * 2 + tap]);
        }
        *(bf16x8*)&pW1[((size_t)(i * 32 + f) * 64 + l) * 8] = v;
    }

    #pragma unroll
    for (int p = 0; p < 4; ++p) {
        int f = p * 4 + (tx >> 6);
        int w = f >> 2, nf = (f >> 1) & 1, ks = f & 1;
        int cpp = w * 32 + nf * 16 + (l & 15);
        int bb = cpp >> 4;
        int c2 = (bb >> 1) * 16 + (cpp & 15);
        const float* src = (bb & 1) ? skw : rw;
        bf16x8 v;
        #pragma unroll
        for (int j = 0; j < 8; ++j) {
            int k = ks * 32 + (l >> 4) * 8 + j;
            v[j] = (short)f2bf(src[((size_t)i * 64 + c2) * 64 + k]);
        }
        *(bf16x8*)&pW2[((size_t)(i * 16 + f) * 64 + l) * 8] = v;
    }

    if (tx < 128) {
        int bb = tx >> 4, r = tx & 15;
        int c1 = (bb & 1 ? 64 : 0) + (bb >> 1) * 16 + r;
        pB1[i * 128 + tx] = db[i * 128 + c1];
        int c2 = (bb >> 1) * 16 + r;
        pB2[i * 128 + tx] = (bb & 1) ? skb[i * 64 + c2] : rb[i * 64 + c2];
    }
}

// ---------- start: h[b][t][c] bf16 t-major ----------
__global__ __launch_bounds__(256) void wn_start(
    const float* __restrict__ x, const float* __restrict__ sw,
    const float* __restrict__ sb, unsigned short* __restrict__ h, int T)
{
    int t = blockIdx.x * blockDim.x + threadIdx.x;
    int b = blockIdx.y;
    float xv = x[(size_t)b * T + t];
    unsigned int pk[32];
    #pragma unroll
    for (int c = 0; c < 64; c += 2) {
        float v0 = fmaf(sw[c], xv, sb[c]);
        float v1 = fmaf(sw[c + 1], xv, sb[c + 1]);
        pk[c >> 1] = (unsigned int)f2bf(v0) | ((unsigned int)f2bf(v1) << 16);
    }
    uint4* dst = (uint4*)(h + ((size_t)b * T + t) * 64);
    #pragma unroll
    for (int i = 0; i < 8; ++i) dst[i] = ((const uint4*)pk)[i];
}

// ---------- fused layer: bf16 h in/out, fp32 skip RMW ----------
__global__ __launch_bounds__(256) void wn_layer(
    const unsigned short* __restrict__ h_in, unsigned short* __restrict__ h_out,
    float* __restrict__ skip_sum,
    const unsigned short* __restrict__ pW1, const unsigned short* __restrict__ pW2,
    const float* __restrict__ pB1, const float* __restrict__ pB2,
    int d, int T, int accum)
{
    __shared__ unsigned short Xs[64 * 128];  // [t][128k] bf16, XOR-swizzled, 16KB
    __shared__ unsigned short Gs[64 * 64];   // [t][64c]  bf16, XOR-swizzled, 8KB

    const int tx = threadIdx.x;
    const int w = tx >> 6;
    const int l = tx & 63;
    const int lr = l & 15;
    const int lg = l >> 4;
    const int b = blockIdx.y;
    const int t0 = blockIdx.x * TTILE;
    const size_t bT = (size_t)b * T;

    // ---- stage X = [h(t-d) || h(t)] : pure 16B bf16 copies ----
    #pragma unroll
    for (int q = 0; q < 4; ++q) {
        int idx = tx * 4 + q;          // 1024 16B-chunks
        int t = idx >> 4;
        int ch = idx & 15;             // 0-7 shifted half, 8-15 current half
        int tt = (ch < 8) ? (t0 + t - d) : (t0 + t);
        bf16x8 v = {0, 0, 0, 0, 0, 0, 0, 0};
        if (tt >= 0)
            v = *(const bf16x8*)(h_in + ((size_t)(bT + tt)) * 64 + (ch & 7) * 8);
        int swz = (ch & 8) | ((ch & 7) ^ (t & 7));
        *(bf16x8*)&Xs[(t * 256 + swz * 16) >> 1] = v;
    }

    // ---- weight fragments (L2-resident, coalesced b128) ----
    bf16x8 W1f[2][4];
    #pragma unroll
    for (int nf = 0; nf < 2; ++nf)
        #pragma unroll
        for (int ks = 0; ks < 4; ++ks)
            W1f[nf][ks] = *(const bf16x8*)&pW1[((size_t)(w * 8 + nf * 4 + ks) * 64 + l) * 8];
    bf16x8 W2f[2][2];
    #pragma unroll
    for (int nf = 0; nf < 2; ++nf)
        #pragma unroll
        for (int ks = 0; ks < 2; ++ks)
            W2f[nf][ks] = *(const bf16x8*)&pW2[((size_t)(w * 4 + nf * 2 + ks) * 64 + l) * 8];

    float bias1[2], bias2[2];
    #pragma unroll
    for (int nf = 0; nf < 2; ++nf) {
        bias1[nf] = pB1[w * 32 + nf * 16 + lr];
        bias2[nf] = pB2[w * 32 + nf * 16 + lr];
    }

    __syncthreads();

    // ---- GEMM1: D1[t][c''] = X[t][k] * W1^T[k][c''] ----
    f32x4 acc1[4][2];
    #pragma unroll
    for (int mf = 0; mf < 4; ++mf) {
        #pragma unroll
        for (int nf = 0; nf < 2; ++nf) {
            f32x4 a = {bias1[nf], bias1[nf], bias1[nf], bias1[nf]};
            #pragma unroll
            for (int ks = 0; ks < 4; ++ks) {
                int tr = mf * 16 + lr;
                int chunk = ks * 4 + lg;
                int swz = (chunk & 8) | ((chunk & 7) ^ (tr & 7));
                bf16x8 av = *(const bf16x8*)&Xs[(tr * 256 + swz * 16) >> 1];
                a = __builtin_amdgcn_mfma_f32_16x16x32_bf16(av, W1f[nf][ks], a, 0, 0, 0);
            }
            acc1[mf][nf] = a;
        }
    }

    // ---- gate -> Gs ----
    const int gc = w * 16 + lr;
    #pragma unroll
    for (int mf = 0; mf < 4; ++mf) {
        #pragma unroll
        for (int r = 0; r < 4; ++r) {
            int tr = mf * 16 + lg * 4 + r;
            float fv = fminf(fmaxf(acc1[mf][0][r], -30.f), 30.f);
            float gv = fminf(fmaxf(acc1[mf][1][r], -30.f), 30.f);
            float e2 = __expf(-2.f * fv);
            float th = (1.f - e2) * __builtin_amdgcn_rcpf(1.f + e2);
            float sg = __builtin_amdgcn_rcpf(1.f + __expf(-gv));
            float gated = th * sg;
            int byte = tr * 128 + (((gc >> 3) ^ (tr & 7)) * 16) + (gc & 7) * 2;
            Gs[byte >> 1] = f2bf(gated);
        }
    }

    // ---- prefetch old skip values (hide RMW-read latency under GEMM2) ----
    float sold[16];
    if (accum) {
        #pragma unroll
        for (int mf = 0; mf < 4; ++mf)
            #pragma unroll
            for (int r = 0; r < 4; ++r) {
                int tr = mf * 16 + lg * 4 + r;
                sold[mf * 4 + r] = skip_sum[(bT + t0 + tr) * 64 + gc];
            }
    } else {
        #pragma unroll
        for (int i = 0; i < 16; ++i) sold[i] = 0.f;
    }

    __syncthreads();

    // ---- GEMM2: D2[t][c2''] = G[t][c] * W2^T[c][c2''] ----
    f32x4 acc2[4][2];
    #pragma unroll
    for (int mf = 0; mf < 4; ++mf) {
        #pragma unroll
        for (int nf = 0; nf < 2; ++nf) {
            f32x4 a = {bias2[nf], bias2[nf], bias2[nf], bias2[nf]};
            #pragma unroll
            for (int ks = 0; ks < 2; ++ks) {
                int tr = mf * 16 + lr;
                int chunk = ks * 4 + lg;
                int swz = chunk ^ (tr & 7);
                bf16x8 av = *(const bf16x8*)&Gs[(tr * 128 + swz * 16) >> 1];
                a = __builtin_amdgcn_mfma_f32_16x16x32_bf16(av, W2f[nf][ks], a, 0, 0, 0);
            }
            acc2[mf][nf] = a;
        }
    }

    // ---- epilogue: h_out = bf16(h_in + res) (h_in read from Xs, bit-identical);
    //      skip_sum = sold + skip ----
    #pragma unroll
    for (int mf = 0; mf < 4; ++mf) {
        #pragma unroll
        for (int r = 0; r < 4; ++r) {
            int tr = mf * 16 + lg * 4 + r;
            int chunk = 8 | ((gc >> 3) ^ (tr & 7));
            unsigned short hb = Xs[(tr * 256 + chunk * 16 + (gc & 7) * 2) >> 1];
            float hres = bf2f(hb) + acc2[mf][0][r];
            size_t gidx = (bT + t0 + tr) * 64 + gc;
            h_out[gidx] = f2bf(hres);
            skip_sum[gidx] = sold[mf * 4 + r] + acc2[mf][1][r];
        }
    }
}

// ---------- end: out = end2( relu(end1(skip_sum)) ) ----------
__global__ __launch_bounds__(256) void wn_end(
    const float* __restrict__ skip, const float* __restrict__ w1,
    const float* __restrict__ b1, const float* __restrict__ w2,
    const float* __restrict__ b2, float* __restrict__ out, int T)
{
    int t = blockIdx.x * blockDim.x + threadIdx.x;
    int b = blockIdx.y;
    const float* row = skip + ((size_t)b * T + t) * 64;
    float sv[SC];
    #pragma unroll
    for (int k = 0; k < SC; k += 4) {
        float4 v = *(const float4*)&row[k];
        sv[k] = v.x; sv[k + 1] = v.y; sv[k + 2] = v.z; sv[k + 3] = v.w;
    }
    float acc = b2[0];
    for (int c = 0; c < SC; ++c) {
        float s = b1[c];
        #pragma unroll
        for (int k = 0; k < SC; k += 4) {
            float4 wv = *(const float4*)&w1[(size_t)c * SC + k];
            s = fmaf(wv.x, sv[k], fmaf(wv.y, sv[k + 1], fmaf(wv.z, sv[k + 2], fmaf(wv.w, sv[k + 3], s))));
        }
        acc = fmaf(w2[c], fmaxf(s, 0.f), acc);
    }
    out[(size_t)b * T + t] = acc;
}

extern "C" void kernel_launch(void* const* d_in, const int* in_sizes, int n_in,
                              void* d_out, int out_size, void* d_ws, size_t ws_size,
                              hipStream_t stream)
{
    const float* x   = (const float*)d_in[0];
    const float* stw = (const float*)d_in[1];
    const float* stb = (const float*)d_in[2];
    const float* dw  = (const float*)d_in[3];
    const float* db  = (const float*)d_in[4];
    const float* rw  = (const float*)d_in[5];
    const float* rb  = (const float*)d_in[6];
    const float* skw = (const float*)d_in[7];
    const float* skb = (const float*)d_in[8];
    const float* e1w = (const float*)d_in[9];
    const float* e1b = (const float*)d_in[10];
    const float* e2w = (const float*)d_in[11];
    const float* e2b = (const float*)d_in[12];

    const int T = 32768;
    const int B = in_sizes[0] / T;

    char* ws = (char*)d_ws;
    const size_t hbytes = (size_t)B * T * 64 * 2;      // 16.8 MB bf16
    unsigned short* h0 = (unsigned short*)ws;
    unsigned short* h1 = (unsigned short*)(ws + hbytes);
    float* sk = (float*)(ws + 2 * hbytes);
    unsigned short* pW1 = (unsigned short*)(ws + 2 * hbytes + (size_t)B * T * 64 * 4);
    unsigned short* pW2 = pW1 + (size_t)NLAYERS * 32 * 64 * 8;
    float* pB1 = (float*)(pW2 + (size_t)NLAYERS * 16 * 64 * 8);
    float* pB2 = pB1 + NLAYERS * 128;

    wn_prep<<<dim3(NLAYERS), 256, 0, stream>>>(dw, rw, skw, db, rb, skb, pW1, pW2, pB1, pB2);
    wn_start<<<dim3(T / 256, B), 256, 0, stream>>>(x, stw, stb, h0, T);

    const unsigned short* hin = h0;
    unsigned short* hout = h1;
    for (int i = 0; i < NLAYERS; ++i) {
        int d = 1 << (i % 10);
        wn_layer<<<dim3(T / TTILE, B), 256, 0, stream>>>(
            hin, hout, sk,
            pW1 + (size_t)i * 32 * 64 * 8, pW2 + (size_t)i * 16 * 64 * 8,
            pB1 + i * 128, pB2 + i * 128,
            d, T, i > 0 ? 1 : 0);
        const unsigned short* tmp = hout;
        hout = (unsigned short*)hin;
        hin = tmp;
    }

    wn_end<<<dim3(T / 256, B), 256, 0, stream>>>(sk, e1w, e1b, e2w, e2b, (float*)d_out, T);
}